// Round 10
// baseline (153.748 us; speedup 1.0000x reference)
//
#include <hip/hip_runtime.h>

typedef unsigned short u16;
typedef __attribute__((ext_vector_type(4))) float f32x4;
typedef __attribute__((ext_vector_type(8))) __bf16 bf16x8;
typedef __attribute__((ext_vector_type(4))) __bf16 bf16x4;
typedef __attribute__((ext_vector_type(4))) unsigned short u16x4;
typedef __attribute__((ext_vector_type(8))) unsigned short u16x8;

// round-to-nearest-even fp32 -> bf16 (used in epilogues / converts)
static __device__ __forceinline__ u16 f2bf(float f) {
    union { float f; unsigned u; } v; v.f = f;
    unsigned r = v.u + 0x7FFFu + ((v.u >> 16) & 1u);
    return (u16)(r >> 16);
}

// v_exp_f32: D = 2^x
static __device__ __forceinline__ float exp2f_fast(float x) {
    float r; asm("v_exp_f32 %0, %1" : "=v"(r) : "v"(x)); return r;
}

// async global->LDS, 16 bytes per lane (dest must be wave-uniform base + lane*16)
static __device__ __forceinline__ void gload16(const u16* g, u16* l) {
    __builtin_amdgcn_global_load_lds(
        (const __attribute__((address_space(1))) unsigned int*)g,
        (__attribute__((address_space(3))) unsigned int*)l, 16, 0, 0);
}

template<int N> static __device__ __forceinline__ void vm_wait() {
    if constexpr (N >= 8)      asm volatile("s_waitcnt vmcnt(8)" ::: "memory");
    else if constexpr (N == 6) asm volatile("s_waitcnt vmcnt(6)" ::: "memory");
    else if constexpr (N == 4) asm volatile("s_waitcnt vmcnt(4)" ::: "memory");
    else if constexpr (N == 3) asm volatile("s_waitcnt vmcnt(3)" ::: "memory");
    else                       asm volatile("s_waitcnt vmcnt(0)" ::: "memory");
}

// swizzled element offset in a [rows][64] u16 tile (flash K/V tiles)
#define SWZ64(row, ec) (((row) * 64) + ((((ec) ^ ((row) & 7))) << 3))

// ---------------- fp32 -> bf16 convert (4 elems/thread) ----------------
__global__ __launch_bounds__(256) void k_cvt(const float* __restrict__ in, u16* __restrict__ out) {
    size_t i = (size_t)blockIdx.x * 256 + threadIdx.x;
    float4 v = ((const float4*)in)[i];
    u16x4 o; o[0] = f2bf(v.x); o[1] = f2bf(v.y); o[2] = f2bf(v.z); o[3] = f2bf(v.w);
    *(u16x4*)(out + i * 4) = o;
}

// ---------------- 4x W [K=1024][N=1024] fp32 -> Wt [N][K] bf16 (scaled), one launch ----------------
__global__ __launch_bounds__(256) void k_wtrans4(
    const float* __restrict__ W0, const float* __restrict__ W1,
    const float* __restrict__ W2, const float* __restrict__ W3,
    u16* __restrict__ T0, u16* __restrict__ T1, u16* __restrict__ T2, u16* __restrict__ T3,
    float s0) {
    const float* W; u16* Tt; float sc;
    switch (blockIdx.z) {
        case 0:  W = W0; Tt = T0; sc = s0;  break;
        case 1:  W = W1; Tt = T1; sc = 1.f; break;
        case 2:  W = W2; Tt = T2; sc = 1.f; break;
        default: W = W3; Tt = T3; sc = 1.f; break;
    }
    __shared__ float tile[32][33];
    int n0 = blockIdx.x * 32, k0 = blockIdx.y * 32;
    int tid = threadIdx.x;
    int r = tid >> 3, c = (tid & 7) * 4;
    float4 v = *(const float4*)(W + (size_t)(k0 + r) * 1024 + n0 + c);
    tile[r][c] = v.x; tile[r][c + 1] = v.y; tile[r][c + 2] = v.z; tile[r][c + 3] = v.w;
    __syncthreads();
    u16x4 o;
    o[0] = f2bf(tile[c][r] * sc);
    o[1] = f2bf(tile[c + 1][r] * sc);
    o[2] = f2bf(tile[c + 2][r] * sc);
    o[3] = f2bf(tile[c + 3][r] * sc);
    *(u16x4*)(Tt + (size_t)(n0 + r) * 1024 + k0 + c) = o;
}

// ---------------- 256-wide GEMM, m201 8-phase schedule ----------------
// BM=256, BK=64, 512 threads (8 waves). BN=256: waves 2M x 4N (wave C 128x64, 4 phases
// per K-tile = mt-half x k-half quadrants); BN=128: 4M x 2N (wave C 64x64, 2 phases).
// Double-buffered 64/48 KB K-tile slots; the next tile's 8 (resp 6) stage calls are
// interleaved 2-3 per phase; boundary vmcnt(0)+barrier once per K-tile (loads got 1-4
// MFMA phases of cover). Full 8-chunk XOR involution swizzle on the 128B rows: LDS pos
// p of row r holds global chunk p^(r&7); read undoes it (canonical k preserved).
// Per phase: {ds_read frags, 2 stage calls, barrier, lgkmcnt(0)+sched_barrier,
// setprio(1), 16 MFMA, setprio(0)}. B-frags held in regs across the two mt-halves.
// mode 0: generic; mode 1: QK split; mode 2: V^T with in-32 column permutation
// pos = g*8+hi*4+r so flash PV A-frags are contiguous b128 in register-P k-order.
template<int BN>
__global__ __launch_bounds__(512, 2) void k_g256(
    const u16* __restrict__ A, const u16* __restrict__ Bt,
    const float* __restrict__ bias, const float* __restrict__ biasK, float qscale,
    u16* __restrict__ obf, u16* __restrict__ obK, float* __restrict__ of32,
    int ldc, int bias_row, int nblk, int mode) {
    constexpr int WN = (BN == 256) ? 4 : 2;       // waves along N
    constexpr int WAVE_M = (BN == 256) ? 128 : 64;
    constexpr int M_REP = WAVE_M / 16;            // 8 or 4
    constexpr int ABUF = 256 * 64;                // u16 per A K-tile buffer (32 KB)
    constexpr int BBUF = BN * 64;
    __shared__ u16 As[2 * ABUF];
    __shared__ u16 Bs[2 * BBUF];
    const int tid = threadIdx.x;
    const int l = tid & 63, w = tid >> 6;
    const int mw = w / WN, nw = w % WN;
    const int fr = l & 15, gg = l >> 4, f4 = gg * 4;
    // XCD-bijective swizzle (grid is always 256 = 32 per XCD)
    const int id = blockIdx.x;
    const int swz = (id & 7) * 32 + (id >> 3);
    const int bm = swz / nblk, bn = swz % nblk;
    const size_t m0 = (size_t)bm * 256, n0v = (size_t)bn * BN;

    // staging: call c covers rows c*64..c*64+63; thread t -> row c*64+(t>>3),
    // source chunk (t&7)^((t>>3)&7) (pre-swizzled source, linear LDS dest)
    const int strow = tid >> 3;
    const int sch = ((tid & 7) ^ (strow & 7)) * 8;
    const u16* Ag = A + (m0 + strow) * 1024 + sch;
    const u16* Bg = Bt + (n0v + strow) * 1024 + sch;
    const int ldst = tid * 8;

    // fragment read: row r, k-half kk, chunk kk*4+gg at LDS pos (kk*4+gg)^(r&7); r&7 = fr&7
    const int kc0 = (gg ^ (fr & 7)) << 3;         // k-half 0; k-half 1 = kc0 ^ 32
    const int abase = (mw * WAVE_M + fr) * 64;
    const int bbase = (nw * 64 + fr) * 64;

    f32x4 acc[M_REP][4] = {};

#define SA(c, J, b) gload16(Ag + (size_t)(c) * 65536 + (size_t)(J) * 64, As + (b) * ABUF + (c) * 4096 + ldst);
#define SB(c, J, b) gload16(Bg + (size_t)(c) * 65536 + (size_t)(J) * 64, Bs + (b) * BBUF + (c) * 4096 + ldst);
#define PH_BAR()                                                        \
    __builtin_amdgcn_s_barrier();                                       \
    asm volatile("s_waitcnt lgkmcnt(0)" ::: "memory");                  \
    __builtin_amdgcn_sched_barrier(0)
#define MFMA16(AB)                                                      \
    __builtin_amdgcn_s_setprio(1);                                      \
    _Pragma("unroll")                                                   \
    for (int mt = 0; mt < 4; ++mt)                                      \
        _Pragma("unroll")                                               \
        for (int nt = 0; nt < 4; ++nt)                                  \
            acc[(AB) + mt][nt] = __builtin_amdgcn_mfma_f32_16x16x32_bf16(afr[mt], bfr[nt], acc[(AB) + mt][nt], 0, 0, 0); \
    __builtin_amdgcn_s_setprio(0)

    // prologue: stage K-tile 0 into buf 0
    SA(0, 0, 0) SA(1, 0, 0) SA(2, 0, 0) SA(3, 0, 0)
    SB(0, 0, 0) SB(1, 0, 0)
    if constexpr (BN == 256) { SB(2, 0, 0) SB(3, 0, 0) }

#define GT256(b, J, STG)                                                                      \
    {                                                                                         \
        asm volatile("s_waitcnt vmcnt(0)" ::: "memory");                                      \
        __builtin_amdgcn_s_barrier();                                                         \
        bf16x8 bfr[4], afr[4];                                                                \
        _Pragma("unroll")                                                                     \
        for (int nt = 0; nt < 4; ++nt) bfr[nt] = *(const bf16x8*)(&Bs[(b) * BBUF + bbase + nt * 1024 + kc0]); \
        _Pragma("unroll")                                                                     \
        for (int mt = 0; mt < 4; ++mt) afr[mt] = *(const bf16x8*)(&As[(b) * ABUF + abase + mt * 1024 + kc0]); \
        if (STG) { SA(0, (J) + 1, (b) ^ 1) SA(1, (J) + 1, (b) ^ 1) }                          \
        PH_BAR();                                                                             \
        MFMA16(0);                                                                            \
        _Pragma("unroll")                                                                     \
        for (int mt = 0; mt < 4; ++mt) afr[mt] = *(const bf16x8*)(&As[(b) * ABUF + abase + (mt + 4) * 1024 + kc0]); \
        if (STG) { SA(2, (J) + 1, (b) ^ 1) SA(3, (J) + 1, (b) ^ 1) }                          \
        PH_BAR();                                                                             \
        MFMA16(4);                                                                            \
        _Pragma("unroll")                                                                     \
        for (int nt = 0; nt < 4; ++nt) bfr[nt] = *(const bf16x8*)(&Bs[(b) * BBUF + bbase + nt * 1024 + (kc0 ^ 32)]); \
        _Pragma("unroll")                                                                     \
        for (int mt = 0; mt < 4; ++mt) afr[mt] = *(const bf16x8*)(&As[(b) * ABUF + abase + mt * 1024 + (kc0 ^ 32)]); \
        if (STG) { SB(0, (J) + 1, (b) ^ 1) SB(1, (J) + 1, (b) ^ 1) }                          \
        PH_BAR();                                                                             \
        MFMA16(0);                                                                            \
        _Pragma("unroll")                                                                     \
        for (int mt = 0; mt < 4; ++mt) afr[mt] = *(const bf16x8*)(&As[(b) * ABUF + abase + (mt + 4) * 1024 + (kc0 ^ 32)]); \
        if (STG) { SB(2, (J) + 1, (b) ^ 1) SB(3, (J) + 1, (b) ^ 1) }                          \
        PH_BAR();                                                                             \
        MFMA16(4);                                                                            \
    }

#define GT128(b, J, STG)                                                                      \
    {                                                                                         \
        asm volatile("s_waitcnt vmcnt(0)" ::: "memory");                                      \
        __builtin_amdgcn_s_barrier();                                                         \
        bf16x8 bfr[4], afr[4];                                                                \
        _Pragma("unroll")                                                                     \
        for (int nt = 0; nt < 4; ++nt) bfr[nt] = *(const bf16x8*)(&Bs[(b) * BBUF + bbase + nt * 1024 + kc0]); \
        _Pragma("unroll")                                                                     \
        for (int mt = 0; mt < 4; ++mt) afr[mt] = *(const bf16x8*)(&As[(b) * ABUF + abase + mt * 1024 + kc0]); \
        if (STG) { SA(0, (J) + 1, (b) ^ 1) SA(1, (J) + 1, (b) ^ 1) SB(0, (J) + 1, (b) ^ 1) }  \
        PH_BAR();                                                                             \
        MFMA16(0);                                                                            \
        _Pragma("unroll")                                                                     \
        for (int nt = 0; nt < 4; ++nt) bfr[nt] = *(const bf16x8*)(&Bs[(b) * BBUF + bbase + nt * 1024 + (kc0 ^ 32)]); \
        _Pragma("unroll")                                                                     \
        for (int mt = 0; mt < 4; ++mt) afr[mt] = *(const bf16x8*)(&As[(b) * ABUF + abase + mt * 1024 + (kc0 ^ 32)]); \
        if (STG) { SA(2, (J) + 1, (b) ^ 1) SA(3, (J) + 1, (b) ^ 1) SB(1, (J) + 1, (b) ^ 1) }  \
        PH_BAR();                                                                             \
        MFMA16(0);                                                                            \
    }

    // K = 1024 -> 16 K-tiles of BK=64
    if constexpr (BN == 256) {
#pragma unroll 1
        for (int j = 0; j < 14; j += 2) { GT256(0, j, 1) GT256(1, j + 1, 1) }
        GT256(0, 14, 1) GT256(1, 15, 0)
    } else {
#pragma unroll 1
        for (int j = 0; j < 14; j += 2) { GT128(0, j, 1) GT128(1, j + 1, 1) }
        GT128(0, 14, 1) GT128(1, 15, 0)
    }
#undef GT256
#undef GT128
#undef SA
#undef SB
#undef PH_BAR
#undef MFMA16

    // epilogue: C/D layout col = lane&15, row = (lane>>4)*4 + r  [HW-verified]
    const int mrow0 = (int)m0 + mw * WAVE_M;
    const int ncol0 = (int)n0v + nw * 64;
    if (mode == 1) {   // QK split (BN==256): cols 0..1023 -> Q (bias*qscale), 1024.. -> K
#pragma unroll
        for (int mt = 0; mt < M_REP; ++mt)
#pragma unroll
            for (int nt = 0; nt < 4; ++nt) {
                const int col = ncol0 + nt * 16 + fr;
                const int seg = col >> 10, colm = col & 1023;
                const float bb = (seg ? biasK[colm] : bias[colm] * qscale);
                u16* op = seg ? obK : obf;
#pragma unroll
                for (int r = 0; r < 4; ++r)
                    op[(size_t)(mrow0 + mt * 16 + f4 + r) * 1024 + colm] = f2bf(acc[mt][nt][r] + bb);
            }
    } else if (mode == 2) {   // V^T: row bias, in-32 column permutation for flash PV b128
#pragma unroll
        for (int mt = 0; mt < M_REP; ++mt) {
            float rb_[4];
#pragma unroll
            for (int r = 0; r < 4; ++r) rb_[r] = bias[mrow0 + mt * 16 + f4 + r];
#pragma unroll
            for (int nt = 0; nt < 4; ++nt) {
                const int col = ncol0 + nt * 16 + fr;
                const int colp = (col & ~31) | (((col >> 2) & 3) << 3) |
                                 (((col >> 4) & 1) << 2) | (col & 3);
#pragma unroll
                for (int r = 0; r < 4; ++r) {
                    const size_t row = (size_t)(mrow0 + mt * 16 + f4 + r);
                    obf[row * (size_t)ldc + colp] = f2bf(acc[mt][nt][r] + rb_[r]);
                }
            }
        }
    } else {
#pragma unroll
        for (int mt = 0; mt < M_REP; ++mt) {
            float rb_[4];
#pragma unroll
            for (int r = 0; r < 4; ++r)
                rb_[r] = bias_row ? bias[mrow0 + mt * 16 + f4 + r] : 0.f;
#pragma unroll
            for (int nt = 0; nt < 4; ++nt) {
                const int col = ncol0 + nt * 16 + fr;
                const float cb = bias_row ? 0.f : bias[col];
#pragma unroll
                for (int r = 0; r < 4; ++r) {
                    const size_t row = (size_t)(mrow0 + mt * 16 + f4 + r);
                    const float vv = acc[mt][nt][r] + cb + rb_[r];
                    if (of32) of32[row * (size_t)ldc + col] = vv;
                    else      obf[row * (size_t)ldc + col] = f2bf(vv);
                }
            }
        }
    }
}

// ---------------- flash attention: T15 lag-1 PV pipeline (unchanged from round 9) ----------------
static __device__ __forceinline__ void qk_tile(const u16* Ks, int fr, int gg,
                                               bf16x8 qA0, bf16x8 qA1, bf16x8 qB0, bf16x8 qB1,
                                               float mA, float mB, f32x4 sA[4], f32x4 sB[4]) {
    __builtin_amdgcn_s_setprio(1);
#pragma unroll
    for (int nt = 0; nt < 4; ++nt) {
        const int rk = nt * 16 + fr;
        const bf16x8 kf0 = *(const bf16x8*)(&Ks[SWZ64(rk, gg)]);
        const bf16x8 kf1 = *(const bf16x8*)(&Ks[SWZ64(rk, gg + 4)]);
        f32x4 z = {-mA, -mA, -mA, -mA};
        z = __builtin_amdgcn_mfma_f32_16x16x32_bf16(kf0, qA0, z, 0, 0, 0);
        z = __builtin_amdgcn_mfma_f32_16x16x32_bf16(kf1, qA1, z, 0, 0, 0);
        sA[nt] = z;
        f32x4 y = {-mB, -mB, -mB, -mB};
        y = __builtin_amdgcn_mfma_f32_16x16x32_bf16(kf0, qB0, y, 0, 0, 0);
        y = __builtin_amdgcn_mfma_f32_16x16x32_bf16(kf1, qB1, y, 0, 0, 0);
        sB[nt] = y;
    }
    __builtin_amdgcn_s_setprio(0);
}

// softmax with no cross-lane ops in the common path (per-lane partial lsum)
static __device__ __forceinline__ void sm_tile(const f32x4 s[4], f32x4 o[4],
                                               float& m, float& lsum, bf16x4 p[4]) {
    float mymax = s[0][0];
#pragma unroll
    for (int nt = 0; nt < 4; ++nt)
#pragma unroll
        for (int r = 0; r < 4; ++r) mymax = fmaxf(mymax, s[nt][r]);
    float ps = 0.f;
#pragma unroll
    for (int nt = 0; nt < 4; ++nt)
#pragma unroll
        for (int r = 0; r < 4; ++r) {
            const float pp = exp2f_fast(s[nt][r]);
            ps += pp; p[nt][r] = (__bf16)pp;
        }
    if (__builtin_expect(__any(mymax > 11.0f), 0)) {   // wave-uniform rare path
        float rm = fmaxf(mymax, __shfl_xor(mymax, 16, 64));
        rm = fmaxf(rm, __shfl_xor(rm, 32, 64));
        const float d = fmaxf(rm, 0.f);
        const float fac = exp2f_fast(-d);
        m += d; lsum *= fac;
#pragma unroll
        for (int mt = 0; mt < 4; ++mt)
#pragma unroll
            for (int r = 0; r < 4; ++r) o[mt][r] *= fac;
        ps = 0.f;
#pragma unroll
        for (int nt = 0; nt < 4; ++nt)
#pragma unroll
            for (int r = 0; r < 4; ++r) {
                const float pp = exp2f_fast(s[nt][r] - d);
                ps += pp; p[nt][r] = (__bf16)pp;
            }
    }
    lsum += ps;
}

// PV with b128 V-frag reads (Vt2 stored k-permuted so register-P k-order is contiguous)
static __device__ __forceinline__ void pv_tile(const u16* Vs, int fr, int gg,
                                               const bf16x4 pA[4], const bf16x4 pB[4],
                                               f32x4 oA[4], f32x4 oB[4]) {
    const bf16x8 BA0 = __builtin_shufflevector(pA[0], pA[1], 0, 1, 2, 3, 4, 5, 6, 7);
    const bf16x8 BA1 = __builtin_shufflevector(pA[2], pA[3], 0, 1, 2, 3, 4, 5, 6, 7);
    const bf16x8 BB0 = __builtin_shufflevector(pB[0], pB[1], 0, 1, 2, 3, 4, 5, 6, 7);
    const bf16x8 BB1 = __builtin_shufflevector(pB[2], pB[3], 0, 1, 2, 3, 4, 5, 6, 7);
    __builtin_amdgcn_s_setprio(1);
#pragma unroll
    for (int mt = 0; mt < 4; ++mt) {
        const int rv = mt * 16 + fr;
        const bf16x8 vk0 = *(const bf16x8*)(&Vs[SWZ64(rv, gg)]);
        const bf16x8 vk1 = *(const bf16x8*)(&Vs[SWZ64(rv, gg + 4)]);
        oA[mt] = __builtin_amdgcn_mfma_f32_16x16x32_bf16(vk0, BA0, oA[mt], 0, 0, 0);
        oA[mt] = __builtin_amdgcn_mfma_f32_16x16x32_bf16(vk1, BA1, oA[mt], 0, 0, 0);
        oB[mt] = __builtin_amdgcn_mfma_f32_16x16x32_bf16(vk0, BB0, oB[mt], 0, 0, 0);
        oB[mt] = __builtin_amdgcn_mfma_f32_16x16x32_bf16(vk1, BB1, oB[mt], 0, 0, 0);
    }
    __builtin_amdgcn_s_setprio(0);
}

// 1D grid 1024 blocks (XCD-bijective swizzle). 4 waves, 32 q-rows/wave (groups A/B).
// 4-slot LDS rotation, counted vmcnt(4) per tile (drain only at tail). Per tile t:
// wait slot t -> barrier -> QK(t) -> stage(t+2) -> PV(t-1) [MFMA] || SM(t) [VALU] -> save P(t).
__global__ __launch_bounds__(256, 2) void k_flash(const u16* __restrict__ Q, const u16* __restrict__ K,
                                                  const u16* __restrict__ Vt2, u16* __restrict__ O) {
    __shared__ u16 Ks[4][64 * 64];
    __shared__ u16 Vs[4][64 * 64];
    const int tid = threadIdx.x;
    const int l = tid & 63, w = tid >> 6;
    const int id = blockIdx.x;
    const int swz = (id & 7) * 128 + (id >> 3);      // bijective XCD swizzle (1024 % 8 == 0)
    const int bh = swz >> 3, qt = swz & 7;
    const int b = bh >> 4, h = bh & 15;
    const int qw = qt * 128 + w * 32;
    const int fr = l & 15, gg = l >> 4, f4 = gg * 4, f8 = gg * 8;

    const u16* qpA = Q + ((size_t)(b * 1024 + qw + fr)) * 1024 + h * 64 + f8;
    const u16* qpB = qpA + 16 * 1024;
    const bf16x8 qA0 = *(const bf16x8*)qpA;
    const bf16x8 qA1 = *(const bf16x8*)(qpA + 32);
    const bf16x8 qB0 = *(const bf16x8*)qpB;
    const bf16x8 qB1 = *(const bf16x8*)(qpB + 32);

    const int jj0 = w * 2, jj1 = w * 2 + 1;
    const int sr0 = jj0 * 8 + (l >> 3), sr1 = jj1 * 8 + (l >> 3);
    const int sc = ((l & 7) ^ (l >> 3)) * 8;
    const u16* kg0 = K + ((size_t)(b * 1024 + sr0)) * 1024 + h * 64 + sc;
    const u16* kg1 = K + ((size_t)(b * 1024 + sr1)) * 1024 + h * 64 + sc;
    const u16* vg0 = Vt2 + ((size_t)(h * 64 + sr0)) * 8192 + b * 1024 + sc;
    const u16* vg1 = Vt2 + ((size_t)(h * 64 + sr1)) * 8192 + b * 1024 + sc;
    const int lk0 = jj0 * 512 + l * 8, lk1 = jj1 * 512 + l * 8;

#define FSTG(S, kt)                                         \
    gload16(kg0 + (size_t)(kt) * 1024, Ks[S] + lk0);        \
    gload16(kg1 + (size_t)(kt) * 1024, Ks[S] + lk1);        \
    gload16(vg0 + (kt), Vs[S] + lk0);                       \
    gload16(vg1 + (kt), Vs[S] + lk1);

    f32x4 oA[4] = {}, oB[4] = {};
    float mA = 0.f, lA = 0.f, mB = 0.f, lB = 0.f;   // lA/lB per-lane partials
    bf16x4 p0A[4], p0B[4], p1A[4], p1B[4];          // ping-pong P sets (static names)

    FSTG(0, 0) FSTG(1, 64)

#define FITER(T, PCA, PCB, PPA, PPB, VMN, DOPV)                              \
    {                                                                        \
        vm_wait<VMN>();                                                      \
        __builtin_amdgcn_s_barrier();                                        \
        f32x4 sA[4], sB[4];                                                  \
        qk_tile(Ks[(T) & 3], fr, gg, qA0, qA1, qB0, qB1, mA, mB, sA, sB);    \
        if ((T) + 2 <= 15) { FSTG((((T) + 2) & 3), ((T) + 2) * 64) }         \
        if (DOPV) pv_tile(Vs[((T) - 1) & 3], fr, gg, PPA, PPB, oA, oB);      \
        sm_tile(sA, oA, mA, lA, PCA);                                        \
        sm_tile(sB, oB, mB, lB, PCB);                                        \
    }

    FITER(0,  p0A, p0B, p1A, p1B, 4, false)
    FITER(1,  p1A, p1B, p0A, p0B, 4, true)
    FITER(2,  p0A, p0B, p1A, p1B, 4, true)
    FITER(3,  p1A, p1B, p0A, p0B, 4, true)
    FITER(4,  p0A, p0B, p1A, p1B, 4, true)
    FITER(5,  p1A, p1B, p0A, p0B, 4, true)
    FITER(6,  p0A, p0B, p1A, p1B, 4, true)
    FITER(7,  p1A, p1B, p0A, p0B, 4, true)
    FITER(8,  p0A, p0B, p1A, p1B, 4, true)
    FITER(9,  p1A, p1B, p0A, p0B, 4, true)
    FITER(10, p0A, p0B, p1A, p1B, 4, true)
    FITER(11, p1A, p1B, p0A, p0B, 4, true)
    FITER(12, p0A, p0B, p1A, p1B, 4, true)
    FITER(13, p1A, p1B, p0A, p0B, 4, true)
    FITER(14, p0A, p0B, p1A, p1B, 4, true)
    FITER(15, p1A, p1B, p0A, p0B, 0, true)
#undef FITER
#undef FSTG
    // drain: PV of the last tile (slot 15&3 = 3, P = p1 sets)
    pv_tile(Vs[3], fr, gg, p1A, p1B, oA, oB);

    // epilogue: cross-lane lsum reduce (once), then O[t][h*64 + mt*16 + f4 + r]
    lA += __shfl_xor(lA, 16, 64); lA += __shfl_xor(lA, 32, 64);
    lB += __shfl_xor(lB, 16, 64); lB += __shfl_xor(lB, 32, 64);
    const float ivA = 1.0f / lA, ivB = 1.0f / lB;
    u16* opA = O + ((size_t)(b * 1024 + qw + fr)) * 1024 + h * 64;
    u16* opB = opA + 16 * 1024;
#pragma unroll
    for (int mt = 0; mt < 4; ++mt) {
        u16x4 oa, ob;
#pragma unroll
        for (int r = 0; r < 4; ++r) { oa[r] = f2bf(oA[mt][r] * ivA); ob[r] = f2bf(oB[mt][r] * ivB); }
        *(u16x4*)(opA + mt * 16 + f4) = oa;
        *(u16x4*)(opB + mt * 16 + f4) = ob;
    }
}

extern "C" void kernel_launch(void* const* d_in, const int* in_sizes, int n_in,
                              void* d_out, int out_size, void* d_ws, size_t ws_size,
                              hipStream_t stream) {
    (void)in_sizes; (void)n_in; (void)out_size; (void)ws_size;
    const float* hs = (const float*)d_in[0];
    const float* Wq = (const float*)d_in[1];
    const float* bq = (const float*)d_in[2];
    const float* Wk = (const float*)d_in[3];
    const float* bk = (const float*)d_in[4];
    const float* Wv = (const float*)d_in[5];
    const float* bv = (const float*)d_in[6];
    const float* Wo = (const float*)d_in[7];
    const float* bo = (const float*)d_in[8];
    float* out = (float*)d_out;
    char* ws = (char*)d_ws;
    const size_t MB = 1024ull * 1024ull;
    u16* Xb  = (u16*)(ws);            // 16 MB (dead after V^T GEMM; reused as attn output Ob)
    u16* Wqt = (u16*)(ws + 16 * MB);  // 2 MB each; Wqt+Wkt adjacent => stacked [2048][1024]
    u16* Wkt = (u16*)(ws + 18 * MB);
    u16* Wvt = (u16*)(ws + 20 * MB);
    u16* Wot = (u16*)(ws + 22 * MB);
    u16* Qb  = (u16*)(ws + 24 * MB);  // 16 MB
    u16* Kb  = (u16*)(ws + 40 * MB);  // 16 MB
    u16* Vt2 = (u16*)(ws + 56 * MB);  // 16 MB: V^T[n][t-permuted], ld=8192 -> 72 MB total
    u16* Ob  = Xb;

    // HD^-0.5 * log2(e) folded into Wq and bq (softmax runs in log2 domain)
    const float SCALE_Q = 0.125f * 1.4426950408889634f;

    k_cvt<<<dim3(8192), dim3(256), 0, stream>>>(hs, Xb);
    k_wtrans4<<<dim3(32, 32, 4), dim3(256), 0, stream>>>(Wq, Wk, Wv, Wo, Wqt, Wkt, Wvt, Wot, SCALE_Q);
    // fused Q+K projection: M=8192, N=2048 over stacked [Wqt;Wkt]; 32x8 = 256 blocks (1/CU)
    k_g256<256><<<dim3(256), dim3(512), 0, stream>>>(Xb, Wqt, bq, bk, SCALE_Q,
                                                     Qb, Kb, nullptr, 1024, 0, 8, 1);
    // V^T = Wv^T * X^T (k-permuted cols): A = Wvt (M=1024), Bt = Xb (N=8192); 4x64 blocks
    k_g256<128><<<dim3(256), dim3(512), 0, stream>>>(Wvt, Xb, bv, nullptr, 1.f,
                                                     Vt2, nullptr, nullptr, 8192, 1, 64, 2);
    k_flash<<<dim3(1024), dim3(256), 0, stream>>>(Qb, Kb, Vt2, Ob);
    // output projection: M=8192, N=1024, f32 out; 32x8 = 256 blocks
    k_g256<128><<<dim3(256), dim3(512), 0, stream>>>(Ob, Wot, bo, nullptr, 1.f,
                                                     nullptr, nullptr, out, 1024, 0, 8, 0);
}